// Round 1
// baseline (745.756 us; speedup 1.0000x reference)
//
#include <hip/hip_runtime.h>
#include <cstdint>
#include <cstddef>

// Static problem geometry (from the reference file)
#define LEN_IN  21760
#define BATCH   2
#define MROWS   (BATCH * LEN_IN)   // 43520 rows for all GEMMs
// Levels: (128,128),(64,64),(32,32),(16,16); starts 0,16384,20480,21504

// ---------------------------------------------------------------------------
// GEMM: C[M,N] = A[M,K] @ B[K,N] + bias[N]   (all row-major, fp32)
// 64x64 tile per block, 256 threads, 4x4 per thread, K-chunk 16.
// Requires M%64==0, N%64==0, K%16==0 (true for all calls here).
// ---------------------------------------------------------------------------
__global__ __launch_bounds__(256) void gemm_bias_kernel(
    const float* __restrict__ A, const float* __restrict__ B,
    const float* __restrict__ bias, float* __restrict__ C,
    int M, int N, int K)
{
  __shared__ float As[16][68];   // [k][m], pad 64->68 keeps 16B alignment, 2-way bank alias only (free)
  __shared__ float Bs[16][64];   // [k][n]

  const int tid = threadIdx.x;
  const int tx = tid & 15;       // column group
  const int ty = tid >> 4;       // row group
  const int rowBase = blockIdx.x * 64;
  const int colBase = blockIdx.y * 64;

  const int ka = tid & 15;       // A-load k
  const int ra = tid >> 4;       // A-load row
  const int nb = tid & 63;       // B-load col
  const int kb = tid >> 6;       // B-load k

  float acc[4][4] = {};

  for (int k0 = 0; k0 < K; k0 += 16) {
#pragma unroll
    for (int rr = 0; rr < 4; ++rr)
      As[ka][ra + 16 * rr] = A[(size_t)(rowBase + ra + 16 * rr) * K + (k0 + ka)];
#pragma unroll
    for (int kk2 = 0; kk2 < 4; ++kk2)
      Bs[kb + 4 * kk2][nb] = B[(size_t)(k0 + kb + 4 * kk2) * N + (colBase + nb)];
    __syncthreads();

#pragma unroll
    for (int kk = 0; kk < 16; ++kk) {
      const float4 av = *reinterpret_cast<const float4*>(&As[kk][ty * 4]);
      const float4 bv = *reinterpret_cast<const float4*>(&Bs[kk][tx * 4]);
      const float a[4] = {av.x, av.y, av.z, av.w};
      const float b[4] = {bv.x, bv.y, bv.z, bv.w};
#pragma unroll
      for (int i = 0; i < 4; ++i)
#pragma unroll
        for (int j = 0; j < 4; ++j)
          acc[i][j] = fmaf(a[i], b[j], acc[i][j]);
    }
    __syncthreads();
  }

  const float4 bb = *reinterpret_cast<const float4*>(&bias[colBase + tx * 4]);
  const float bias4[4] = {bb.x, bb.y, bb.z, bb.w};
#pragma unroll
  for (int i = 0; i < 4; ++i) {
    const int row = rowBase + ty * 4 + i;
    float4 o;
    o.x = acc[i][0] + bias4[0];
    o.y = acc[i][1] + bias4[1];
    o.z = acc[i][2] + bias4[2];
    o.w = acc[i][3] + bias4[3];
    *reinterpret_cast<float4*>(&C[(size_t)row * N + colBase + tx * 4]) = o;
  }
}

// ---------------------------------------------------------------------------
// Sampling: one block per (n,q). 256 threads = 8 heads x 32 dims.
// Softmax over 16 (L*P) logits per head, then 16 bilinear samples per head.
// ---------------------------------------------------------------------------
__global__ __launch_bounds__(256) void sample_kernel(
    const float* __restrict__ value,   // (BATCH, LEN_IN, 256)  c = m*32+d
    const float* __restrict__ offs,    // (BATCH, LEN_Q, 256)   c = (((m*4+l)*4+p)*2+xy)
    const float* __restrict__ logits,  // (BATCH, LEN_Q, 128)   c = m*16 + l*4 + p
    const float* __restrict__ refpts,  // (BATCH, LEN_Q, 4, 2)
    float* __restrict__ outp)          // (BATCH, LEN_Q, 256)   c = m*32+d
{
  __shared__ float s_off[256];
  __shared__ float s_w[128];
  __shared__ float s_ref[8];

  const int q = blockIdx.x;       // n*LEN_IN + qi
  const int tid = threadIdx.x;

  s_off[tid] = offs[(size_t)q * 256 + tid];
  if (tid < 128) s_w[tid] = logits[(size_t)q * 128 + tid];
  if (tid < 8)  s_ref[tid] = refpts[(size_t)q * 8 + tid];
  __syncthreads();

  // softmax per head over 16 entries (8 lanes do it serially; tiny)
  if (tid < 8) {
    float mx = -1e30f;
#pragma unroll
    for (int i = 0; i < 16; ++i) mx = fmaxf(mx, s_w[tid * 16 + i]);
    float sum = 0.f;
#pragma unroll
    for (int i = 0; i < 16; ++i) {
      const float e = expf(s_w[tid * 16 + i] - mx);
      s_w[tid * 16 + i] = e;
      sum += e;
    }
    const float inv = 1.f / sum;
#pragma unroll
    for (int i = 0; i < 16; ++i) s_w[tid * 16 + i] *= inv;
  }
  __syncthreads();

  const int m = tid >> 5;
  const int d = tid & 31;
  const int n = q / LEN_IN;
  const float* vb = value + (size_t)n * LEN_IN * 256 + m * 32 + d;

  const int   Hs[4]     = {128, 64, 32, 16};
  const int   starts[4] = {0, 16384, 20480, 21504};

  float acc = 0.f;
#pragma unroll
  for (int l = 0; l < 4; ++l) {
    const int H = Hs[l], W = Hs[l], st = starts[l];
    const float rx = s_ref[l * 2 + 0];
    const float ry = s_ref[l * 2 + 1];
    const float* base = vb + (size_t)st * 256;
#pragma unroll
    for (int p = 0; p < 4; ++p) {
      const int oidx = ((m * 4 + l) * 4 + p) * 2;
      const float ox = s_off[oidx + 0];
      const float oy = s_off[oidx + 1];
      const float aw = s_w[m * 16 + l * 4 + p];

      const float x = (rx + ox) * (float)W - 0.5f;
      const float y = (ry + oy) * (float)H - 0.5f;
      const float xf = floorf(x), yf = floorf(y);
      const int x0 = (int)xf, y0 = (int)yf;
      const float wx = x - xf, wy = y - yf;

      const bool xv0 = (x0 >= 0) && (x0 < W);
      const bool xv1 = (x0 + 1 >= 0) && (x0 + 1 < W);
      const bool yv0 = (y0 >= 0) && (y0 < H);
      const bool yv1 = (y0 + 1 >= 0) && (y0 + 1 < H);

      float s = 0.f;
      if (yv0) {
        const float* rowp = base + (ptrdiff_t)(y0 * W) * 256;
        if (xv0) s = fmaf(rowp[(ptrdiff_t)x0 * 256],       (1.f - wx) * (1.f - wy), s);
        if (xv1) s = fmaf(rowp[(ptrdiff_t)(x0 + 1) * 256],        wx  * (1.f - wy), s);
      }
      if (yv1) {
        const float* rowp = base + (ptrdiff_t)((y0 + 1) * W) * 256;
        if (xv0) s = fmaf(rowp[(ptrdiff_t)x0 * 256],       (1.f - wx) * wy, s);
        if (xv1) s = fmaf(rowp[(ptrdiff_t)(x0 + 1) * 256],        wx  * wy, s);
      }
      acc = fmaf(aw, s, acc);
    }
  }
  outp[(size_t)q * 256 + tid] = acc;
}

// ---------------------------------------------------------------------------
extern "C" void kernel_launch(void* const* d_in, const int* in_sizes, int n_in,
                              void* d_out, int out_size, void* d_ws, size_t ws_size,
                              hipStream_t stream) {
  const float* query   = (const float*)d_in[0];
  const float* refpts  = (const float*)d_in[1];
  const float* flatten = (const float*)d_in[2];
  // d_in[3] spatial_shapes, d_in[4] level_start_index: static, hard-coded.
  const float* Wv   = (const float*)d_in[5];
  const float* bv   = (const float*)d_in[6];
  const float* Woff = (const float*)d_in[7];
  const float* boff = (const float*)d_in[8];
  const float* Wa   = (const float*)d_in[9];
  const float* ba   = (const float*)d_in[10];
  const float* Wo   = (const float*)d_in[11];
  const float* bo   = (const float*)d_in[12];
  float* out = (float*)d_out;

  // Workspace layout (floats): value | offs | logits | out_pre  (~156 MB)
  float* ws     = (float*)d_ws;
  float* value  = ws;                                   // MROWS*256
  float* offsb  = value  + (size_t)MROWS * 256;         // MROWS*256
  float* logit  = offsb  + (size_t)MROWS * 256;         // MROWS*128
  float* outp   = logit  + (size_t)MROWS * 128;         // MROWS*256

  const dim3 blk(256);
  const int mtiles = MROWS / 64;  // 680

  // value = flatten @ Wv + bv
  gemm_bias_kernel<<<dim3(mtiles, 4), blk, 0, stream>>>(flatten, Wv, bv, value, MROWS, 256, 256);
  // offs = query @ Woff + boff
  gemm_bias_kernel<<<dim3(mtiles, 4), blk, 0, stream>>>(query, Woff, boff, offsb, MROWS, 256, 256);
  // logits = query @ Wa + ba
  gemm_bias_kernel<<<dim3(mtiles, 2), blk, 0, stream>>>(query, Wa, ba, logit, MROWS, 128, 256);
  // sampling + softmax + head-dim weighted sum
  sample_kernel<<<dim3(MROWS), blk, 0, stream>>>(value, offsb, logit, refpts, outp);
  // out = out_pre @ Wo + bo
  gemm_bias_kernel<<<dim3(mtiles, 4), blk, 0, stream>>>(outp, Wo, bo, out, MROWS, 256, 256);
}

// Round 2
// 512.247 us; speedup vs baseline: 1.4559x; 1.4559x over previous
//
#include <hip/hip_runtime.h>
#include <cstdint>
#include <cstddef>

// Static problem geometry (from the reference file)
#define LEN_IN  21760
#define BATCH   2
#define MROWS   (BATCH * LEN_IN)   // 43520 rows for all GEMMs
// Levels: (128,128),(64,64),(32,32),(16,16); starts 0,16384,20480,21504

// ---------------------------------------------------------------------------
// GEMM: C[M,N] = A[M,K] @ B[K,N] + bias[N]   (row-major fp32)
// 128x128 tile, 256 threads, 8x8 micro-tile as 4 quadrants (+0/+64), K-chunk 16.
// Requires M%128==0, N%128==0, K%16==0 (true for all calls here).
// ---------------------------------------------------------------------------
__global__ __launch_bounds__(256) void gemm_bias_128(
    const float* __restrict__ A, const float* __restrict__ B,
    const float* __restrict__ bias, float* __restrict__ C,
    int M, int N, int K)
{
  __shared__ float As[16][132];   // [k][m] padded: write 2-way alias only (free)
  __shared__ float Bs[16][128];   // [k][n]

  const int tid = threadIdx.x;
  const int tx = tid & 15;        // column group (cols tx*4 and 64+tx*4)
  const int ty = tid >> 4;        // row group    (rows ty*4 and 64+ty*4)
  const int rowBase = blockIdx.x * 128;
  const int colBase = blockIdx.y * 128;

  const int ka = tid & 15;        // A-load k
  const int ra = tid >> 4;        // A-load row base (8 rows: ra+16*rr)
  const int nb = tid & 127;       // B-load col
  const int kb = tid >> 7;        // B-load k base (8 ks: kb*8+i)

  float acc[2][2][4][4] = {};

  for (int k0 = 0; k0 < K; k0 += 16) {
#pragma unroll
    for (int rr = 0; rr < 8; ++rr)
      As[ka][ra + 16 * rr] = A[(size_t)(rowBase + ra + 16 * rr) * K + (k0 + ka)];
#pragma unroll
    for (int i = 0; i < 8; ++i)
      Bs[kb * 8 + i][nb] = B[(size_t)(k0 + kb * 8 + i) * N + (colBase + nb)];
    __syncthreads();

#pragma unroll
    for (int kk = 0; kk < 16; ++kk) {
      const float4 a0 = *reinterpret_cast<const float4*>(&As[kk][ty * 4]);
      const float4 a1 = *reinterpret_cast<const float4*>(&As[kk][64 + ty * 4]);
      const float4 b0 = *reinterpret_cast<const float4*>(&Bs[kk][tx * 4]);
      const float4 b1 = *reinterpret_cast<const float4*>(&Bs[kk][64 + tx * 4]);
      const float a[2][4] = {{a0.x, a0.y, a0.z, a0.w}, {a1.x, a1.y, a1.z, a1.w}};
      const float b[2][4] = {{b0.x, b0.y, b0.z, b0.w}, {b1.x, b1.y, b1.z, b1.w}};
#pragma unroll
      for (int qi = 0; qi < 2; ++qi)
#pragma unroll
        for (int qj = 0; qj < 2; ++qj)
#pragma unroll
          for (int i = 0; i < 4; ++i)
#pragma unroll
            for (int j = 0; j < 4; ++j)
              acc[qi][qj][i][j] = fmaf(a[qi][i], b[qj][j], acc[qi][qj][i][j]);
    }
    __syncthreads();
  }

#pragma unroll
  for (int qj = 0; qj < 2; ++qj) {
    const int col = colBase + qj * 64 + tx * 4;
    const float4 bb = *reinterpret_cast<const float4*>(&bias[col]);
#pragma unroll
    for (int qi = 0; qi < 2; ++qi)
#pragma unroll
      for (int i = 0; i < 4; ++i) {
        const int row = rowBase + qi * 64 + ty * 4 + i;
        float4 o;
        o.x = acc[qi][qj][i][0] + bb.x;
        o.y = acc[qi][qj][i][1] + bb.y;
        o.z = acc[qi][qj][i][2] + bb.z;
        o.w = acc[qi][qj][i][3] + bb.w;
        *reinterpret_cast<float4*>(&C[(size_t)row * N + col]) = o;
      }
  }
}

// ---------------------------------------------------------------------------
// Sampling: one block per (n,q). Phase 1 (128 thr): per (head,point) compute
// 4 corner byte-offsets + pre-multiplied weights (zeroed if OOB), pack in LDS.
// Phase 2 (256 thr = 8 heads x 32 dims): 64 x {ds_read_b64 broadcast, gather,
// fmac} — branch-free, no duplicated coordinate math.
// ---------------------------------------------------------------------------
__global__ __launch_bounds__(256) void sample_kernel(
    const float* __restrict__ value,   // (BATCH, LEN_IN, 256)  c = m*32+d
    const float* __restrict__ offs,    // (BATCH, LEN_Q, 256)   c = (((m*4+l)*4+p)*2+xy)
    const float* __restrict__ logits,  // (BATCH, LEN_Q, 128)   c = m*16 + l*4 + p
    const float* __restrict__ refpts,  // (BATCH, LEN_Q, 4, 2)
    float* __restrict__ outp)          // (BATCH, LEN_Q, 256)   c = m*32+d
{
  __shared__ float  s_off[256];
  __shared__ float  s_w[128];
  __shared__ float  s_ref[8];
  __shared__ float2 s_pair[512];   // {byte-offset (bitcast int), weight} per (m,lp,corner)

  const int q = blockIdx.x;
  const int tid = threadIdx.x;

  s_off[tid] = offs[(size_t)q * 256 + tid];
  if (tid < 128) s_w[tid] = logits[(size_t)q * 128 + tid];
  if (tid < 8)   s_ref[tid] = refpts[(size_t)q * 8 + tid];
  __syncthreads();

  if (tid < 8) {   // softmax per head over 16 entries
    float mx = -1e30f;
#pragma unroll
    for (int i = 0; i < 16; ++i) mx = fmaxf(mx, s_w[tid * 16 + i]);
    float sum = 0.f;
#pragma unroll
    for (int i = 0; i < 16; ++i) {
      const float e = expf(s_w[tid * 16 + i] - mx);
      s_w[tid * 16 + i] = e;
      sum += e;
    }
    const float inv = 1.f / sum;
#pragma unroll
    for (int i = 0; i < 16; ++i) s_w[tid * 16 + i] *= inv;
  }
  __syncthreads();

  if (tid < 128) {
    const int m = tid >> 4, lp = tid & 15, l = lp >> 2;
    const int Hs[4]     = {128, 64, 32, 16};
    const int starts[4] = {0, 16384, 20480, 21504};
    const int W = Hs[l], H = W, st = starts[l];
    const int oidx = ((m * 4 + l) * 4 + (lp & 3)) * 2;
    const float x = (s_ref[l * 2 + 0] + s_off[oidx + 0]) * (float)W - 0.5f;
    const float y = (s_ref[l * 2 + 1] + s_off[oidx + 1]) * (float)H - 0.5f;
    const float aw = s_w[tid];  // s_w[m*16+lp] == s_w[tid]
    const float xf = floorf(x), yf = floorf(y);
    const int x0 = (int)xf, y0 = (int)yf;
    const float wx = x - xf, wy = y - yf;
#pragma unroll
    for (int c = 0; c < 4; ++c) {
      const int dx = c & 1, dy = c >> 1;
      const int xi = x0 + dx, yi = y0 + dy;
      const bool valid = (xi >= 0) & (xi < W) & (yi >= 0) & (yi < H);
      const float w = (dx ? wx : 1.f - wx) * (dy ? wy : 1.f - wy) * aw;
      const int boff = valid ? (st + yi * W + xi) * 1024 : 0;   // bytes: *256 floats *4
      float2 pr;
      pr.x = __int_as_float(boff);
      pr.y = valid ? w : 0.f;
      s_pair[tid * 4 + c] = pr;
    }
  }
  __syncthreads();

  const int m = tid >> 5, d = tid & 31;
  const int n = q / LEN_IN;
  const char* vb = (const char*)(value + (size_t)n * LEN_IN * 256 + m * 32 + d);

  float acc = 0.f;
  const int base = m * 64;
#pragma unroll 16
  for (int i = 0; i < 64; ++i) {
    const float2 pr = s_pair[base + i];
    const float v = *reinterpret_cast<const float*>(vb + __float_as_int(pr.x));
    acc = fmaf(pr.y, v, acc);
  }
  outp[(size_t)q * 256 + tid] = acc;
}

// ---------------------------------------------------------------------------
extern "C" void kernel_launch(void* const* d_in, const int* in_sizes, int n_in,
                              void* d_out, int out_size, void* d_ws, size_t ws_size,
                              hipStream_t stream) {
  const float* query   = (const float*)d_in[0];
  const float* refpts  = (const float*)d_in[1];
  const float* flatten = (const float*)d_in[2];
  // d_in[3] spatial_shapes, d_in[4] level_start_index: static, hard-coded.
  const float* Wv   = (const float*)d_in[5];
  const float* bv   = (const float*)d_in[6];
  const float* Woff = (const float*)d_in[7];
  const float* boff = (const float*)d_in[8];
  const float* Wa   = (const float*)d_in[9];
  const float* ba   = (const float*)d_in[10];
  const float* Wo   = (const float*)d_in[11];
  const float* bo   = (const float*)d_in[12];
  float* out = (float*)d_out;

  // Workspace layout (floats): value | offs | logits | out_pre  (~156 MB)
  float* ws     = (float*)d_ws;
  float* value  = ws;                                   // MROWS*256
  float* offsb  = value  + (size_t)MROWS * 256;         // MROWS*256
  float* logit  = offsb  + (size_t)MROWS * 256;         // MROWS*128
  float* outp   = logit  + (size_t)MROWS * 128;         // MROWS*256

  const dim3 blk(256);
  const int mtiles = MROWS / 128;  // 340

  // value = flatten @ Wv + bv
  gemm_bias_128<<<dim3(mtiles, 2), blk, 0, stream>>>(flatten, Wv, bv, value, MROWS, 256, 256);
  // offs = query @ Woff + boff
  gemm_bias_128<<<dim3(mtiles, 2), blk, 0, stream>>>(query, Woff, boff, offsb, MROWS, 256, 256);
  // logits = query @ Wa + ba
  gemm_bias_128<<<dim3(mtiles, 1), blk, 0, stream>>>(query, Wa, ba, logit, MROWS, 128, 256);
  // sampling + softmax + head-dim weighted sum
  sample_kernel<<<dim3(MROWS), blk, 0, stream>>>(value, offsb, logit, refpts, outp);
  // out = out_pre @ Wo + bo
  gemm_bias_128<<<dim3(mtiles, 2), blk, 0, stream>>>(outp, Wo, bo, out, MROWS, 256, 256);
}

// Round 3
// 366.684 us; speedup vs baseline: 2.0338x; 1.3970x over previous
//
#include <hip/hip_runtime.h>
#include <cstdint>
#include <cstddef>

// Static problem geometry
#define LEN_IN  21760
#define BATCH   2
#define MROWS   (BATCH * LEN_IN)   // 43520
// Levels: (128,128),(64,64),(32,32),(16,16); starts 0,16384,20480,21504

typedef short  short8  __attribute__((ext_vector_type(8)));
typedef float  floatx4 __attribute__((ext_vector_type(4)));
typedef _Float16 h2v   __attribute__((ext_vector_type(2)));

__device__ __forceinline__ unsigned short f2bf(float f) {
  unsigned u = __float_as_uint(f);
  u += 0x7fff + ((u >> 16) & 1);           // round-to-nearest-even
  return (unsigned short)(u >> 16);
}
__device__ __forceinline__ float bf2f(unsigned short s) {
  return __uint_as_float(((unsigned)s) << 16);
}

// ---------------------------------------------------------------------------
// Split-bf16 conversion: x -> (hi, lo) with hi+lo ~ fp32(x) to ~2^-17 rel.
// ---------------------------------------------------------------------------
__global__ __launch_bounds__(256) void cvt_split_kernel(
    const float* __restrict__ x, short* __restrict__ h, short* __restrict__ l, int n4)
{
  const int i = blockIdx.x * 256 + threadIdx.x;
  if (i >= n4) return;
  const float4 v = *reinterpret_cast<const float4*>(&x[i * 4]);
  const float vv[4] = {v.x, v.y, v.z, v.w};
  ushort4 hh, ll;
  unsigned short* hp = &hh.x;
  unsigned short* lp = &ll.x;
#pragma unroll
  for (int k = 0; k < 4; ++k) {
    const unsigned short hi = f2bf(vv[k]);
    hp[k] = hi;
    lp[k] = f2bf(vv[k] - bf2f(hi));
  }
  *reinterpret_cast<ushort4*>(&h[i * 4]) = hh;
  *reinterpret_cast<ushort4*>(&l[i * 4]) = ll;
}

// Weight transpose+split: src fp32 [K=256][N] -> dst bf16 [N][256] (hi,lo)
__global__ __launch_bounds__(256) void cvt_wT_kernel(
    const float* __restrict__ src, short* __restrict__ h, short* __restrict__ l, int N)
{
  const int n = blockIdx.x;       // 0..N-1
  const int k = threadIdx.x;      // 0..255
  const float v = src[(size_t)k * N + n];
  const unsigned short hi = f2bf(v);
  h[(size_t)n * 256 + k] = hi;
  l[(size_t)n * 256 + k] = f2bf(v - bf2f(hi));
}

// ---------------------------------------------------------------------------
// Split-bf16 MFMA GEMM: C[M,N] = (Ah+Al)[M,K] @ (Bh+Bl)[K,N] + bias
// B given TRANSPOSED: Bt[N][K].  128x128 tile, 256 thr (4 waves, each 64x64
// as 4x4 of 16x16x32 bf16 MFMA).  K%32==0, M%128==0, N%128==0.
// OUTMODE 0: fp32   1: _Float16
// ---------------------------------------------------------------------------
template<int OUTMODE>
__global__ __launch_bounds__(256) void gemm_mfma(
    const short* __restrict__ Ah, const short* __restrict__ Al,
    const short* __restrict__ Bth, const short* __restrict__ Btl,
    const float* __restrict__ bias, void* __restrict__ Cout,
    int M, int N, int K)
{
  __shared__ short As[2][128 * 40];   // [part][row*40 + k], pad 32->40
  __shared__ short Bs[2][128 * 40];

  const int tid  = threadIdx.x;
  const int lane = tid & 63;
  const int wave = tid >> 6;
  const int l15  = lane & 15;
  const int quad = lane >> 4;
  const int wr   = (wave & 1) * 64;   // wave row offset in tile
  const int wc   = (wave >> 1) * 64;  // wave col offset in tile
  const int rowBase = blockIdx.x * 128;
  const int colBase = blockIdx.y * 128;

  const int r  = tid >> 2;            // staging row 0..63 (+64 second pass)
  const int hc = (tid & 3) * 8;       // staging k-offset (halves)

  floatx4 acc[4][4] = {};

  for (int k0 = 0; k0 < K; k0 += 32) {
    if (k0) __syncthreads();
#pragma unroll
    for (int pass = 0; pass < 2; ++pass) {
      const int row = r + pass * 64;
      const size_t ga = (size_t)(rowBase + row) * K + k0 + hc;
      const size_t gb = (size_t)(colBase + row) * K + k0 + hc;
      *reinterpret_cast<float4*>(&As[0][row * 40 + hc]) = *reinterpret_cast<const float4*>(&Ah[ga]);
      *reinterpret_cast<float4*>(&As[1][row * 40 + hc]) = *reinterpret_cast<const float4*>(&Al[ga]);
      *reinterpret_cast<float4*>(&Bs[0][row * 40 + hc]) = *reinterpret_cast<const float4*>(&Bth[gb]);
      *reinterpret_cast<float4*>(&Bs[1][row * 40 + hc]) = *reinterpret_cast<const float4*>(&Btl[gb]);
    }
    __syncthreads();

    short8 ah[4], al[4], bh[4], bl[4];
#pragma unroll
    for (int i = 0; i < 4; ++i) {
      ah[i] = *reinterpret_cast<const short8*>(&As[0][(wr + i * 16 + l15) * 40 + quad * 8]);
      al[i] = *reinterpret_cast<const short8*>(&As[1][(wr + i * 16 + l15) * 40 + quad * 8]);
      bh[i] = *reinterpret_cast<const short8*>(&Bs[0][(wc + i * 16 + l15) * 40 + quad * 8]);
      bl[i] = *reinterpret_cast<const short8*>(&Bs[1][(wc + i * 16 + l15) * 40 + quad * 8]);
    }
#pragma unroll
    for (int i = 0; i < 4; ++i)
#pragma unroll
      for (int j = 0; j < 4; ++j) {
        acc[i][j] = __builtin_amdgcn_mfma_f32_16x16x32_bf16(ah[i], bh[j], acc[i][j], 0, 0, 0);
        acc[i][j] = __builtin_amdgcn_mfma_f32_16x16x32_bf16(ah[i], bl[j], acc[i][j], 0, 0, 0);
        acc[i][j] = __builtin_amdgcn_mfma_f32_16x16x32_bf16(al[i], bh[j], acc[i][j], 0, 0, 0);
      }
  }

  // Epilogue: C/D layout col=lane&15, row=quad*4+reg (m89/m91-verified)
#pragma unroll
  for (int j = 0; j < 4; ++j) {
    const int col = colBase + wc + j * 16 + l15;
    const float bj = bias[col];
#pragma unroll
    for (int i = 0; i < 4; ++i) {
#pragma unroll
      for (int rg = 0; rg < 4; ++rg) {
        const int row = rowBase + wr + i * 16 + quad * 4 + rg;
        const float v = acc[i][j][rg] + bj;
        if (OUTMODE == 0)
          ((float*)Cout)[(size_t)row * N + col] = v;
        else
          ((_Float16*)Cout)[(size_t)row * N + col] = (_Float16)v;
      }
    }
  }
}

// ---------------------------------------------------------------------------
// Sampler: 128 thr/block, one query. Phase1 (all 128): per (head,point) the 4
// corner byte-offsets + premultiplied weights -> s_pair[corner][head] (pattern
// conflict-free for phase2). Phase2: 8 heads x 16 lanes, half2 gather per lane.
// Writes out_pre as split-bf16 (hi,lo).
// ---------------------------------------------------------------------------
__global__ __launch_bounds__(128) void sample_kernel(
    const _Float16* __restrict__ value16, // (B, LEN_IN, 256) f16
    const float* __restrict__ offs,       // (B, LQ, 256) f32
    const _Float16* __restrict__ logits16,// (B, LQ, 128) f16
    const float* __restrict__ refpts,     // (B, LQ, 4, 2) f32
    short* __restrict__ outh, short* __restrict__ outl) // (B, LQ, 256) bf16 split
{
  __shared__ float  s_off[256];
  __shared__ float  s_w[128];
  __shared__ float  s_ref[8];
  __shared__ float2 s_pair[512];   // [i][m] at i*8+m : {byte-offset, weight}

  const int q = blockIdx.x;
  const int tid = threadIdx.x;

  const float2 t2 = reinterpret_cast<const float2*>(offs + (size_t)q * 256)[tid];
  s_off[2 * tid]     = t2.x;
  s_off[2 * tid + 1] = t2.y;
  s_w[tid] = (float)logits16[(size_t)q * 128 + tid];
  if (tid < 8) s_ref[tid] = refpts[(size_t)q * 8 + tid];
  __syncthreads();

  if (tid < 8) {   // softmax per head over 16
    float mx = -1e30f;
#pragma unroll
    for (int i = 0; i < 16; ++i) mx = fmaxf(mx, s_w[tid * 16 + i]);
    float sum = 0.f;
#pragma unroll
    for (int i = 0; i < 16; ++i) {
      const float e = expf(s_w[tid * 16 + i] - mx);
      s_w[tid * 16 + i] = e;
      sum += e;
    }
    const float inv = 1.f / sum;
#pragma unroll
    for (int i = 0; i < 16; ++i) s_w[tid * 16 + i] *= inv;
  }
  __syncthreads();

  {
    const int m = tid >> 4, lp = tid & 15, l = lp >> 2;
    const int Hs[4]     = {128, 64, 32, 16};
    const int starts[4] = {0, 16384, 20480, 21504};
    const int W = Hs[l], H = W, st = starts[l];
    const int oidx = ((m * 4 + l) * 4 + (lp & 3)) * 2;
    const float x = (s_ref[l * 2 + 0] + s_off[oidx + 0]) * (float)W - 0.5f;
    const float y = (s_ref[l * 2 + 1] + s_off[oidx + 1]) * (float)H - 0.5f;
    const float aw = s_w[m * 16 + lp];
    const float xf = floorf(x), yf = floorf(y);
    const int x0 = (int)xf, y0 = (int)yf;
    const float wx = x - xf, wy = y - yf;
#pragma unroll
    for (int c = 0; c < 4; ++c) {
      const int dx = c & 1, dy = c >> 1;
      const int xi = x0 + dx, yi = y0 + dy;
      const bool valid = (xi >= 0) & (xi < W) & (yi >= 0) & (yi < H);
      const float w = (dx ? wx : 1.f - wx) * (dy ? wy : 1.f - wy) * aw;
      float2 pr;
      pr.x = __int_as_float(valid ? (st + yi * W + xi) * 512 : 0);  // 256 halves * 2B
      pr.y = valid ? w : 0.f;
      s_pair[(lp * 4 + c) * 8 + m] = pr;
    }
  }
  __syncthreads();

  const int m = tid >> 4, dp = tid & 15;
  const int n = q / LEN_IN;
  const char* base = (const char*)value16 + (size_t)n * LEN_IN * 512 + m * 64 + dp * 4;

  float a0 = 0.f, a1 = 0.f;
#pragma unroll 16
  for (int i = 0; i < 64; ++i) {
    const float2 pr = s_pair[i * 8 + m];
    const h2v v = *reinterpret_cast<const h2v*>(base + __float_as_int(pr.x));
    a0 = fmaf(pr.y, (float)v[0], a0);
    a1 = fmaf(pr.y, (float)v[1], a1);
  }

  const size_t oi = (size_t)q * 256 + m * 32 + dp * 2;
  const unsigned short h0 = f2bf(a0), h1 = f2bf(a1);
  ushort2 hh, ll;
  hh.x = h0; hh.y = h1;
  ll.x = f2bf(a0 - bf2f(h0)); ll.y = f2bf(a1 - bf2f(h1));
  *reinterpret_cast<ushort2*>(&outh[oi]) = hh;
  *reinterpret_cast<ushort2*>(&outl[oi]) = ll;
}

// ---------------------------------------------------------------------------
extern "C" void kernel_launch(void* const* d_in, const int* in_sizes, int n_in,
                              void* d_out, int out_size, void* d_ws, size_t ws_size,
                              hipStream_t stream) {
  const float* query   = (const float*)d_in[0];
  const float* refpts  = (const float*)d_in[1];
  const float* flatten = (const float*)d_in[2];
  const float* Wv   = (const float*)d_in[5];
  const float* bv   = (const float*)d_in[6];
  const float* Woff = (const float*)d_in[7];
  const float* boff = (const float*)d_in[8];
  const float* Wa   = (const float*)d_in[9];
  const float* ba   = (const float*)d_in[10];
  const float* Wo   = (const float*)d_in[11];
  const float* bo   = (const float*)d_in[12];
  float* out = (float*)d_out;

  // Workspace layout (123.5 MB total):
  //   q_h | q_l | f_h | f_l | value16 | logits16 | weights...
  // Aliases: offs(fp32) reuses [f_h,f_l] after value GEMM; out_pre reuses [q_h,q_l].
  const size_t NE = (size_t)MROWS * 256;       // 11,141,120
  short* q_h = (short*)d_ws;
  short* q_l = q_h + NE;
  short* f_h = q_l + NE;
  short* f_l = f_h + NE;
  float* offsb = (float*)f_h;                  // alias (same 44.57 MB)
  _Float16* value16  = (_Float16*)(f_l + NE);
  _Float16* logits16 = value16 + NE;
  short* WvT_h   = (short*)(logits16 + (size_t)MROWS * 128);
  short* WvT_l   = WvT_h + 256 * 256;
  short* WoffT_h = WvT_l + 256 * 256;
  short* WoffT_l = WoffT_h + 256 * 256;
  short* WaT_h   = WoffT_l + 256 * 256;
  short* WaT_l   = WaT_h + 128 * 256;
  short* WoT_h   = WaT_l + 128 * 256;
  short* WoT_l   = WoT_h + 256 * 256;
  short* outp_h = q_h;                         // alias (query dead after GEMMs)
  short* outp_l = q_l;

  const int n4 = (int)(NE / 4);                // 2,785,280
  const int mtiles = MROWS / 128;              // 340

  // Conversions
  cvt_split_kernel<<<dim3((n4 + 255) / 256), dim3(256), 0, stream>>>(query,   q_h, q_l, n4);
  cvt_split_kernel<<<dim3((n4 + 255) / 256), dim3(256), 0, stream>>>(flatten, f_h, f_l, n4);
  cvt_wT_kernel<<<dim3(256), dim3(256), 0, stream>>>(Wv,   WvT_h,   WvT_l,   256);
  cvt_wT_kernel<<<dim3(256), dim3(256), 0, stream>>>(Woff, WoffT_h, WoffT_l, 256);
  cvt_wT_kernel<<<dim3(128), dim3(256), 0, stream>>>(Wa,   WaT_h,   WaT_l,   128);
  cvt_wT_kernel<<<dim3(256), dim3(256), 0, stream>>>(Wo,   WoT_h,   WoT_l,   256);

  // value = flatten @ Wv + bv   (fp16 out; must run BEFORE offs overwrites f)
  gemm_mfma<1><<<dim3(mtiles, 2), dim3(256), 0, stream>>>(f_h, f_l, WvT_h, WvT_l, bv, value16, MROWS, 256, 256);
  // offs = query @ Woff + boff  (fp32 out, into f region)
  gemm_mfma<0><<<dim3(mtiles, 2), dim3(256), 0, stream>>>(q_h, q_l, WoffT_h, WoffT_l, boff, offsb, MROWS, 256, 256);
  // logits = query @ Wa + ba    (fp16 out)
  gemm_mfma<1><<<dim3(mtiles, 1), dim3(256), 0, stream>>>(q_h, q_l, WaT_h, WaT_l, ba, logits16, MROWS, 128, 256);
  // sampling (writes out_pre split-bf16 into q region)
  sample_kernel<<<dim3(MROWS), dim3(128), 0, stream>>>(value16, offsb, logits16, refpts, outp_h, outp_l);
  // out = out_pre @ Wo + bo     (fp32 to d_out)
  gemm_mfma<0><<<dim3(mtiles, 2), dim3(256), 0, stream>>>(outp_h, outp_l, WoT_h, WoT_l, bo, out, MROWS, 256, 256);
}

// Round 4
// 313.670 us; speedup vs baseline: 2.3775x; 1.1690x over previous
//
#include <hip/hip_runtime.h>
#include <cstdint>
#include <cstddef>

// Static problem geometry
#define LEN_IN  21760
#define BATCH   2
#define MROWS   (BATCH * LEN_IN)   // 43520 = 128 * 340
// Levels: (128,128),(64,64),(32,32),(16,16); starts 0,16384,20480,21504

typedef short    sv8 __attribute__((ext_vector_type(8)));   // 8 bf16
typedef _Float16 hv8 __attribute__((ext_vector_type(8)));   // 8 f16
typedef float    fv4 __attribute__((ext_vector_type(4)));

__device__ __forceinline__ unsigned short f2bf(float f) {
  unsigned u = __float_as_uint(f);
  u += 0x7fff + ((u >> 16) & 1);           // RNE
  return (unsigned short)(u >> 16);
}
__device__ __forceinline__ float bf2f(unsigned short s) {
  return __uint_as_float(((unsigned)s) << 16);
}

// ---------------------------------------------------------------------------
// Weight prep (1 launch): transpose K-major -> [N][K], f16 or split-bf16.
// ---------------------------------------------------------------------------
__global__ __launch_bounds__(256) void cvt_weights(
    const float* __restrict__ Wv, const float* __restrict__ Woff,
    const float* __restrict__ Wa, const float* __restrict__ Wo,
    _Float16* __restrict__ WvT, short* __restrict__ WoffTh, short* __restrict__ WoffTl,
    _Float16* __restrict__ WaT, short* __restrict__ WoTh, short* __restrict__ WoTl)
{
  const int b = blockIdx.x, k = threadIdx.x;
  if (b < 256) {
    WvT[(size_t)b * 256 + k] = (_Float16)Wv[(size_t)k * 256 + b];
  } else if (b < 512) {
    const int n = b - 256;
    const float v = Woff[(size_t)k * 256 + n];
    const unsigned short h = f2bf(v);
    WoffTh[(size_t)n * 256 + k] = h;
    WoffTl[(size_t)n * 256 + k] = f2bf(v - bf2f(h));
  } else if (b < 640) {
    const int n = b - 512;
    WaT[(size_t)n * 256 + k] = (_Float16)Wa[(size_t)k * 128 + n];
  } else {
    const int n = b - 640;
    const float v = Wo[(size_t)k * 256 + n];
    const unsigned short h = f2bf(v);
    WoTh[(size_t)n * 256 + k] = h;
    WoTl[(size_t)n * 256 + k] = f2bf(v - bf2f(h));
  }
}

// ---------------------------------------------------------------------------
// f16 MFMA GEMM: C[M,TN] = f16(A32[M,256]) @ f16Bt[TN,256]^T + bias
// 128 x TN tile (grid.y==1), 256 thr = 4 waves (2x2), fused fp32->f16 on A.
// outf16: write _Float16, else float. Stride = TN.
// ---------------------------------------------------------------------------
template<int TN>
__global__ __launch_bounds__(256, 2) void gemm_f16(
    const float* __restrict__ A, const _Float16* __restrict__ Bt,
    const float* __restrict__ bias, void* __restrict__ Cout, int outf16)
{
  constexpr int K = 256;
  constexpr int JF = TN / 32;
  __shared__ _Float16 As[128 * 32];
  __shared__ _Float16 Bs[TN * 32];

  const int tid = threadIdx.x, lane = tid & 63, wave = tid >> 6;
  const int l15 = lane & 15, quad = lane >> 4;
  const int wr = (wave & 1) * 64, wc = (wave >> 1) * (TN / 2);
  const int rowBase = blockIdx.x * 128;
  const int rs = tid >> 2, ss = (tid & 3) * 8;

  fv4 acc[4][JF] = {};

  for (int k0 = 0; k0 < K; k0 += 32) {
    if (k0) __syncthreads();
#pragma unroll
    for (int p2 = 0; p2 < 2; ++p2) {      // A: 128 rows, cvt fp32->f16
      const int row = p2 * 64 + rs;
      const float4 f0 = *(const float4*)&A[(size_t)(rowBase + row) * K + k0 + ss];
      const float4 f1 = *(const float4*)&A[(size_t)(rowBase + row) * K + k0 + ss + 4];
      hv8 h;
      h[0] = (_Float16)f0.x; h[1] = (_Float16)f0.y; h[2] = (_Float16)f0.z; h[3] = (_Float16)f0.w;
      h[4] = (_Float16)f1.x; h[5] = (_Float16)f1.y; h[6] = (_Float16)f1.z; h[7] = (_Float16)f1.w;
      *(hv8*)&As[row * 32 + ss] = h;
    }
#pragma unroll
    for (int p2 = 0; p2 < TN / 64; ++p2) { // B: TN rows of [n][k]
      const int row = p2 * 64 + rs;
      *(hv8*)&Bs[row * 32 + ss] = *(const hv8*)&Bt[(size_t)row * K + k0 + ss];
    }
    __syncthreads();

    hv8 a[4];
#pragma unroll
    for (int i = 0; i < 4; ++i) a[i] = *(const hv8*)&As[(wr + i * 16 + l15) * 32 + quad * 8];
#pragma unroll
    for (int j = 0; j < JF; ++j) {
      const hv8 b = *(const hv8*)&Bs[(wc + j * 16 + l15) * 32 + quad * 8];
#pragma unroll
      for (int i = 0; i < 4; ++i)
        acc[i][j] = __builtin_amdgcn_mfma_f32_16x16x32_f16(a[i], b, acc[i][j], 0, 0, 0);
    }
  }

#pragma unroll
  for (int j = 0; j < JF; ++j) {
    const int col = wc + j * 16 + l15;
    const float bj = bias[col];
#pragma unroll
    for (int i = 0; i < 4; ++i)
#pragma unroll
      for (int rg = 0; rg < 4; ++rg) {
        const int row = rowBase + wr + i * 16 + quad * 4 + rg;
        const float v = acc[i][j][rg] + bj;
        if (outf16) ((_Float16*)Cout)[(size_t)row * TN + col] = (_Float16)v;
        else        ((float*)Cout)[(size_t)row * TN + col] = v;
      }
  }
}

// ---------------------------------------------------------------------------
// Split-bf16 MFMA GEMM (3 MFMAs: hh+hl+lh), 128x256 tile, fp32 out.
// PRE=0: A fp32, split in staging. PRE=1: A pre-split (Ah,Al bf16).
// ---------------------------------------------------------------------------
template<int PRE>
__global__ __launch_bounds__(256, 2) void gemm_split(
    const float* __restrict__ A32,
    const short* __restrict__ Ah, const short* __restrict__ Al,
    const short* __restrict__ Bth, const short* __restrict__ Btl,
    const float* __restrict__ bias, float* __restrict__ C)
{
  constexpr int K = 256, TN = 256, JF = 8;
  __shared__ short Ash[128 * 32], Asl[128 * 32];
  __shared__ short Bsh[256 * 32], Bsl[256 * 32];

  const int tid = threadIdx.x, lane = tid & 63, wave = tid >> 6;
  const int l15 = lane & 15, quad = lane >> 4;
  const int wr = (wave & 1) * 64, wc = (wave >> 1) * 128;
  const int rowBase = blockIdx.x * 128;
  const int rs = tid >> 2, ss = (tid & 3) * 8;

  fv4 acc[4][JF] = {};

  for (int k0 = 0; k0 < K; k0 += 32) {
    if (k0) __syncthreads();
#pragma unroll
    for (int p2 = 0; p2 < 2; ++p2) {
      const int row = p2 * 64 + rs;
      if (PRE) {
        *(sv8*)&Ash[row * 32 + ss] = *(const sv8*)&Ah[(size_t)(rowBase + row) * K + k0 + ss];
        *(sv8*)&Asl[row * 32 + ss] = *(const sv8*)&Al[(size_t)(rowBase + row) * K + k0 + ss];
      } else {
        const float4 f0 = *(const float4*)&A32[(size_t)(rowBase + row) * K + k0 + ss];
        const float4 f1 = *(const float4*)&A32[(size_t)(rowBase + row) * K + k0 + ss + 4];
        const float fv[8] = {f0.x, f0.y, f0.z, f0.w, f1.x, f1.y, f1.z, f1.w};
        sv8 hh, ll;
#pragma unroll
        for (int e = 0; e < 8; ++e) {
          const unsigned short h = f2bf(fv[e]);
          hh[e] = (short)h;
          ll[e] = (short)f2bf(fv[e] - bf2f(h));
        }
        *(sv8*)&Ash[row * 32 + ss] = hh;
        *(sv8*)&Asl[row * 32 + ss] = ll;
      }
    }
#pragma unroll
    for (int p2 = 0; p2 < 4; ++p2) {
      const int row = p2 * 64 + rs;
      *(sv8*)&Bsh[row * 32 + ss] = *(const sv8*)&Bth[(size_t)row * K + k0 + ss];
      *(sv8*)&Bsl[row * 32 + ss] = *(const sv8*)&Btl[(size_t)row * K + k0 + ss];
    }
    __syncthreads();

    sv8 ah[4], al[4];
#pragma unroll
    for (int i = 0; i < 4; ++i) {
      ah[i] = *(const sv8*)&Ash[(wr + i * 16 + l15) * 32 + quad * 8];
      al[i] = *(const sv8*)&Asl[(wr + i * 16 + l15) * 32 + quad * 8];
    }
#pragma unroll
    for (int j = 0; j < JF; ++j) {
      const sv8 bh = *(const sv8*)&Bsh[(wc + j * 16 + l15) * 32 + quad * 8];
      const sv8 bl = *(const sv8*)&Bsl[(wc + j * 16 + l15) * 32 + quad * 8];
#pragma unroll
      for (int i = 0; i < 4; ++i) {
        acc[i][j] = __builtin_amdgcn_mfma_f32_16x16x32_bf16(ah[i], bh, acc[i][j], 0, 0, 0);
        acc[i][j] = __builtin_amdgcn_mfma_f32_16x16x32_bf16(ah[i], bl, acc[i][j], 0, 0, 0);
        acc[i][j] = __builtin_amdgcn_mfma_f32_16x16x32_bf16(al[i], bh, acc[i][j], 0, 0, 0);
      }
    }
  }

#pragma unroll
  for (int j = 0; j < JF; ++j) {
    const int col = wc + j * 16 + l15;
    const float bj = bias[col];
#pragma unroll
    for (int i = 0; i < 4; ++i)
#pragma unroll
      for (int rg = 0; rg < 4; ++rg) {
        const int row = rowBase + wr + i * 16 + quad * 4 + rg;
        C[(size_t)row * TN + col] = acc[i][j][rg] + bj;
      }
  }
}

// ---------------------------------------------------------------------------
// Sampler: 256 thr / block, 8 queries per block.
//  softmax (64 thr, one per (q,m)) -> s_attn[p*64+q*8+m]
//  phase 1 (256 thr x 4 items, i=p*64+q*8+m): corner byte-offset + weight,
//    writes s_pair[c][i] lane-consecutively (conflict-free)
//  phase 2: lane=(q,m,j): 64 x {b64 LDS (16 banks, 4-way bcast), dwordx4
//    gather of 8 f16 dims, 8 fma_mix}. Writes out_pre split-bf16.
// ---------------------------------------------------------------------------
__global__ __launch_bounds__(256) void sample_kernel(
    const _Float16* __restrict__ value16,  // (B, LEN_IN, 256) f16
    const float* __restrict__ offs,        // (B, LQ, 256) f32
    const _Float16* __restrict__ logits16, // (B, LQ, 128) f16
    const float* __restrict__ refpts,      // (B, LQ, 4, 2) f32
    short* __restrict__ outh, short* __restrict__ outl)
{
  __shared__ float2 s_pair[4][1024];
  __shared__ float  s_attn[1024];

  const int tid = threadIdx.x;
  const int qBase = blockIdx.x * 8;

  if (tid < 64) {   // softmax per (q,m) over 16
    const int q = tid >> 3, m = tid & 7;
    const size_t lb = (size_t)(qBase + q) * 128 + m * 16;
    float w[16];
#pragma unroll
    for (int i = 0; i < 16; ++i) w[i] = (float)logits16[lb + i];
    float mx = w[0];
#pragma unroll
    for (int i = 1; i < 16; ++i) mx = fmaxf(mx, w[i]);
    float sum = 0.f;
#pragma unroll
    for (int i = 0; i < 16; ++i) { w[i] = expf(w[i] - mx); sum += w[i]; }
    const float inv = 1.f / sum;
#pragma unroll
    for (int p = 0; p < 16; ++p) s_attn[p * 64 + q * 8 + m] = w[p] * inv;
  }
  __syncthreads();

#pragma unroll
  for (int k = 0; k < 4; ++k) {
    const int i = tid + 256 * k;
    const int p = i >> 6, q = (i >> 3) & 7, m = i & 7;
    const int l = p >> 2, pp = p & 3;
    const int qg = qBase + q;
    const float2 rp = *(const float2*)&refpts[(size_t)qg * 8 + l * 2];
    const float2 of = *(const float2*)&offs[(size_t)qg * 256 + ((m * 4 + l) * 4 + pp) * 2];
    const float aw = s_attn[p * 64 + q * 8 + m];
    const int W = 128 >> l;
    const int st = (l == 0) ? 0 : (l == 1) ? 16384 : (l == 2) ? 20480 : 21504;
    const float x = (rp.x + of.x) * (float)W - 0.5f;
    const float y = (rp.y + of.y) * (float)W - 0.5f;
    const float xf = floorf(x), yf = floorf(y);
    const int x0 = (int)xf, y0 = (int)yf;
    const float wx = x - xf, wy = y - yf;
#pragma unroll
    for (int c = 0; c < 4; ++c) {
      const int dx = c & 1, dy = c >> 1;
      const int xi = x0 + dx, yi = y0 + dy;
      const bool valid = (xi >= 0) & (xi < W) & (yi >= 0) & (yi < W);
      const float w = (dx ? wx : 1.f - wx) * (dy ? wy : 1.f - wy) * aw;
      float2 pr;
      pr.x = __int_as_float(valid ? (st + yi * W + xi) * 512 : 0);  // bytes
      pr.y = valid ? w : 0.f;
      s_pair[c][i] = pr;
    }
  }
  __syncthreads();

  const int wave = tid >> 6, lane = tid & 63;
  const int qloc = wave * 2 + (lane >> 5);
  const int sub = lane & 31, m = sub >> 2, j = sub & 3;
  const int qg = qBase + qloc;
  const int n = (qg >= LEN_IN) ? 1 : 0;
  const char* base = (const char*)(value16 + (size_t)n * LEN_IN * 256) + m * 64 + j * 16;
  const int lb = qloc * 8 + m;

  float acc[8] = {0.f, 0.f, 0.f, 0.f, 0.f, 0.f, 0.f, 0.f};
#pragma unroll 8
  for (int i = 0; i < 64; ++i) {
    const int c = i & 3, p = i >> 2;
    const float2 pr = s_pair[c][p * 64 + lb];
    const hv8 v = *(const hv8*)(base + __float_as_int(pr.x));
#pragma unroll
    for (int e = 0; e < 8; ++e) acc[e] = fmaf(pr.y, (float)v[e], acc[e]);
  }

  sv8 hh, ll;
#pragma unroll
  for (int e = 0; e < 8; ++e) {
    const unsigned short h = f2bf(acc[e]);
    hh[e] = (short)h;
    ll[e] = (short)f2bf(acc[e] - bf2f(h));
  }
  const size_t ob = (size_t)qg * 256 + m * 32 + j * 8;
  *(sv8*)&outh[ob] = hh;
  *(sv8*)&outl[ob] = ll;
}

// ---------------------------------------------------------------------------
extern "C" void kernel_launch(void* const* d_in, const int* in_sizes, int n_in,
                              void* d_out, int out_size, void* d_ws, size_t ws_size,
                              hipStream_t stream) {
  const float* query   = (const float*)d_in[0];
  const float* refpts  = (const float*)d_in[1];
  const float* flatten = (const float*)d_in[2];
  const float* Wv   = (const float*)d_in[5];
  const float* bv   = (const float*)d_in[6];
  const float* Woff = (const float*)d_in[7];
  const float* boff = (const float*)d_in[8];
  const float* Wa   = (const float*)d_in[9];
  const float* ba   = (const float*)d_in[10];
  const float* Wo   = (const float*)d_in[11];
  const float* bo   = (const float*)d_in[12];
  float* out = (float*)d_out;

  // Workspace (~123 MB): value16 | offs | logits16 | outh | outl | weights
  const size_t NE = (size_t)MROWS * 256;           // 11,141,120
  _Float16* value16  = (_Float16*)d_ws;            // NE halves
  float*    offsb    = (float*)(value16 + NE);     // NE floats
  _Float16* logits16 = (_Float16*)(offsb + NE);    // NE/2 halves
  short*    outh     = (short*)(logits16 + NE / 2);
  short*    outl     = outh + NE;
  _Float16* WvT16    = (_Float16*)(outl + NE);
  short*    WoffTh   = (short*)(WvT16 + 256 * 256);
  short*    WoffTl   = WoffTh + 256 * 256;
  _Float16* WaT16    = (_Float16*)(WoffTl + 256 * 256);
  short*    WoTh     = (short*)(WaT16 + 128 * 256);
  short*    WoTl     = WoTh + 256 * 256;

  const dim3 blk(256);
  const int mtiles = MROWS / 128;  // 340

  cvt_weights<<<dim3(896), blk, 0, stream>>>(Wv, Woff, Wa, Wo,
      WvT16, WoffTh, WoffTl, WaT16, WoTh, WoTl);

  // value = f16(flatten @ Wv + bv)
  gemm_f16<256><<<dim3(mtiles), blk, 0, stream>>>(flatten, WvT16, bv, value16, 1);
  // offs = query @ Woff + boff  (split-bf16, fp32 out)
  gemm_split<0><<<dim3(mtiles), blk, 0, stream>>>(query, nullptr, nullptr, WoffTh, WoffTl, boff, offsb);
  // logits = f16(query @ Wa + ba)
  gemm_f16<128><<<dim3(mtiles), blk, 0, stream>>>(query, WaT16, ba, logits16, 1);
  // sampling -> out_pre (split-bf16)
  sample_kernel<<<dim3(MROWS / 8), blk, 0, stream>>>(value16, offsb, logits16, refpts, outh, outl);
  // out = out_pre @ Wo + bo
  gemm_split<1><<<dim3(mtiles), blk, 0, stream>>>(nullptr, outh, outl, WoTh, WoTl, bo, out);
}